// Round 2
// baseline (143.146 us; speedup 1.0000x reference)
//
#include <hip/hip_runtime.h>
#include <hip/hip_bf16.h>

// KAN linear == GEMM M=8192, N=512, K=4096 (8 Chebyshev/silu feats per input,
// basis_0 folded into bias). Round 11: R9's verified structure (4 waves,
// 64mx128n block, 32x32x16 MFMA, split-K x2, per-wave gen) with ONE change:
// K-step halved (32/half, 64 iters) and both K-halves merged into unified
// 64-short Bs rows (preserves the XOR-8 conflict-free bank geometry).
// LDS 72->36 KB => 4 blocks/CU (16 waves/CU, 4 waves/SIMD) vs R9's 2 —
// cross-block overlap hides the per-iter barrier/vmcnt drain (m114 mechanism).
// R10's shared-gen/8-wave rewrite failed numerically; reverted to proven math.
#define IN_FEAT 512
#define OUT_FEAT 512
#define NTOK 8192
#define KDIM 4096

typedef short bf16x8 __attribute__((ext_vector_type(8)));
typedef float f32x16 __attribute__((ext_vector_type(16)));

static __device__ inline short f2bf(float f) {
    union { float f; unsigned u; } v; v.f = f;
    unsigned u = v.u;
    u += 0x7fffu + ((u >> 16) & 1u);   // RNE
    return (short)(u >> 16);
}

static __device__ inline unsigned pack2bf(float f0, float f1) {
    union { float f; unsigned u; } a, b; a.f = f0; b.f = f1;
    return __builtin_amdgcn_perm(b.u + 0x8000u, a.u + 0x8000u, 0x07060302u);
}

// 8 basis features of one (token,input): [silu(xc), xc, T2..T7]
static __device__ inline bf16x8 gen_chunk(float xv) {
    float xc = fminf(fmaxf(xv, -1.f), 1.f);
    float e  = __expf(-xc);
    float bse = xc * __builtin_amdgcn_rcpf(1.f + e);
    float b2 = 2.f * xc * xc - 1.f;
    float b3 = 2.f * xc * b2 - 1.f;
    float b4 = 2.f * xc * b3 - 1.f;
    float b5 = 2.f * xc * b4 - 1.f;
    float b6 = 2.f * xc * b5 - 1.f;
    float b7 = 2.f * xc * b6 - 1.f;
    union { uint4 u; bf16x8 v; } r;
    r.u.x = pack2bf(bse, xc);
    r.u.y = pack2bf(b2, b3);
    r.u.z = pack2bf(b4, b5);
    r.u.w = pack2bf(b6, b7);
    return r.v;
}

static __device__ inline void gload_lds16(const short* g, short* l) {
    __builtin_amdgcn_global_load_lds(
        (const __attribute__((address_space(1))) unsigned int*)g,
        (__attribute__((address_space(3))) unsigned int*)l,
        16, 0, 0);
}

// ---------------- prep: W bf16 [512 x 4096] + folded bias ----------------
__global__ __launch_bounds__(256) void kan_prep(
    const float* __restrict__ coeff, const float* __restrict__ scale_base,
    const float* __restrict__ scale_spline, const float* __restrict__ base_bias,
    short* __restrict__ Wb, float* __restrict__ bias)
{
    int o = blockIdx.x;
    int tid = threadIdx.x;
    float local = 0.f;
#pragma unroll
    for (int rep = 0; rep < 2; ++rep) {
        int i = tid + rep * 256;
        size_t oi = (size_t)o * IN_FEAT + i;
        const float4* c4 = (const float4*)(coeff + oi * 8);
        float4 ca = c4[0], cb = c4[1];
        float ss = scale_spline[oi];
        float sb = scale_base[oi];
        local += base_bias[oi] + ss * ca.x;
        bf16x8 w;
        w[0] = f2bf(sb);
        w[1] = f2bf(ss * ca.y); w[2] = f2bf(ss * ca.z); w[3] = f2bf(ss * ca.w);
        w[4] = f2bf(ss * cb.x); w[5] = f2bf(ss * cb.y); w[6] = f2bf(ss * cb.z);
        w[7] = f2bf(ss * cb.w);
        *(bf16x8*)(Wb + (size_t)o * KDIM + (size_t)i * 8) = w;
    }
    __shared__ float red[4];
    for (int off = 32; off > 0; off >>= 1) local += __shfl_down(local, off, 64);
    int lane = tid & 63, wv = tid >> 6;
    if (lane == 0) red[wv] = local;
    __syncthreads();
    if (tid == 0) bias[o] = red[0] + red[1] + red[2] + red[3];
}

// ------- 32x32x16 fused GEMM, in-block split-K x2, 36 KB LDS (4 blk/CU) -------
#define RSTR 67   // epilogue reduce stride (floats): (lane*67)%32 distinct -> 2-way max

__global__ __launch_bounds__(256, 4) void kan_gemm11(
    const float* __restrict__ x, const short* __restrict__ Wb,
    const float* __restrict__ bias, float* __restrict__ out)
{
    // LDS pool, 36 KB:
    //   Bs: [2][128 rows][8 slots][8 shorts]  32 KB (dbuf; slots 0-3 = khalf0,
    //        4-7 = khalf1 of this iter's 32-elem step; XOR-swizzled phys slots)
    //   xsl:[2][8 slots][64 tokens] f32        4 KB (dbuf, raw x slab)
    __shared__ __align__(16) short POOL[18432];
    short* Bs  = POOL;                    // [2][8192]
    float* xsl = (float*)(POOL + 16384);  // [2][512]

    int tid = threadIdx.x;
    int nb = blockIdx.x & 3;         // XCD j sees nb=j&3 -> 1 MB W slice per XCD L2
    int mb = blockIdx.x >> 2;        // 128 m-tiles
    int m0 = mb * 64, o0 = nb * 128;

    int lane = tid & 63, wv = tid >> 6;
    int wn = wv & 1, kk = wv >> 1;   // wave = 64m x 64n on K-half kk
    int l31 = lane & 31, half = lane >> 5;

    f32x16 acc[2][2];                // [fm][fn], 32x32 each
#pragma unroll
    for (int a = 0; a < 2; ++a)
#pragma unroll
        for (int b = 0; b < 2; ++b) acc[a][b] = (f32x16)0.f;

    // B DMA: wave wv stages rows [wv*32,+32), unified 64-short rows, 4 calls.
    // phys slot s at row r holds logical chunk g = s ^ (r&7); source pre-swizzled.
    // logical g: g>>2 = k-half, g&3 = input-within-step; 8 shorts = 8 features.
    int rg = lane >> 3;              // row within 8-row group; row&7 == rg
    int g  = (lane & 7) ^ rg;
    const short* Bg = Wb + (size_t)(o0 + wv * 32 + rg) * KDIM
                         + (g >> 2) * 2048 + (g & 3) * 8;

    // x staging: thread -> (row, half xh, pair xq); float2 covers 2 of the 4
    // inputs of one k-half for this iter. slot s = xh*4 + xq*2 + {0,1}.
    int xrow = tid >> 2, p = tid & 3;
    int xh = p >> 1, xq = p & 1;
    const float* xg = x + (size_t)(m0 + xrow) * IN_FEAT + xh * 256 + xq * 2;
    int sb0 = (xh * 4 + xq * 2) * 64 + xrow;

#define STAGE(buf, it)                                                        \
    {                                                                         \
        short* bd_ = Bs + (buf) * 8192 + wv * 2048;                           \
        const short* bg_ = Bg + (size_t)(it) * 32;                            \
        _Pragma("unroll")                                                     \
        for (int j = 0; j < 4; ++j)                                           \
            gload_lds16(bg_ + (size_t)j * 8 * KDIM, bd_ + j * 512);           \
        float2 v_ = *(const float2*)(xg + (size_t)(it) * 4);                  \
        float* xd_ = xsl + (buf) * 512 + sb0;                                 \
        xd_[0]  = v_.x;                                                       \
        xd_[64] = v_.y;                                                       \
    }

    STAGE(0, 0);
    int cur = 0;
    for (int it = 0; it < 64; ++it, cur ^= 1) {   // K-half = 2048 = 64 x 32
        __syncthreads();             // buf[cur] ready (DMA+writes drained); buf[nxt] free
        if (it < 63) { int nxt = cur ^ 1; STAGE(nxt, it + 1); }
        const short* Bsc = Bs + cur * 8192;
        const float* xc_ = xsl + cur * 512;
#pragma unroll
        for (int istep = 0; istep < 2; ++istep) {   // 2 k-steps of 16 (2 inputs each)
            int clog = kk * 4 + istep * 2 + half;   // this lane's logical chunk
            bf16x8 bfr[2], af[2];
#pragma unroll
            for (int fn = 0; fn < 2; ++fn) {
                int row = wn * 64 + fn * 32 + l31;
                bfr[fn] = *(const bf16x8*)(Bsc + row * 64 + ((clog ^ (row & 7)) * 8));
            }
#pragma unroll
            for (int fm = 0; fm < 2; ++fm)          // xsl slot numbering == clog
                af[fm] = gen_chunk(xc_[clog * 64 + fm * 32 + l31]);
#pragma unroll
            for (int fm = 0; fm < 2; ++fm)
#pragma unroll
                for (int fn = 0; fn < 2; ++fn)
                    acc[fm][fn] = __builtin_amdgcn_mfma_f32_32x32x16_bf16(
                        af[fm], bfr[fn], acc[fm][fn], 0, 0, 0);
        }
    }
#undef STAGE

    // ---- epilogue: reduce the 2 K-halves through LDS (reuse pool), store ----
    float* rbuf = (float*)POOL;      // 9216 floats; max index 8572 < 9216
    int base = (wn * 64 + lane) * RSTR;
    __syncthreads();                 // everyone done reading Bs/xsl
    if (kk == 1) {
#pragma unroll
        for (int fm = 0; fm < 2; ++fm)
#pragma unroll
            for (int fn = 0; fn < 2; ++fn)
#pragma unroll
                for (int r = 0; r < 16; ++r)
                    rbuf[base + (fm * 2 + fn) * 16 + r] = acc[fm][fn][r];
    }
    __syncthreads();
    if (kk == 0) {
        // C/D layout (32x32): col = lane&31, row = (r&3) + 8*(r>>2) + 4*(lane>>5)
#pragma unroll
        for (int fn = 0; fn < 2; ++fn) {
            int o = o0 + wn * 64 + fn * 32 + l31;
            float bv = bias[o];
#pragma unroll
            for (int fm = 0; fm < 2; ++fm) {
#pragma unroll
                for (int r = 0; r < 16; ++r) {
                    float v = acc[fm][fn][r] + rbuf[base + (fm * 2 + fn) * 16 + r] + bv;
                    int token = m0 + fm * 32 + (r & 3) + 8 * (r >> 2) + 4 * half;
                    out[(size_t)token * OUT_FEAT + o] = v;
                }
            }
        }
    }
}

extern "C" void kernel_launch(void* const* d_in, const int* in_sizes, int n_in,
                              void* d_out, int out_size, void* d_ws, size_t ws_size,
                              hipStream_t stream) {
    const float* x            = (const float*)d_in[0];
    const float* coeff        = (const float*)d_in[1];
    const float* scale_base   = (const float*)d_in[2];
    const float* scale_spline = (const float*)d_in[3];
    const float* base_bias    = (const float*)d_in[4];
    float* out = (float*)d_out;

    short* Wb   = (short*)d_ws;                                  // 4 MB
    float* bias = (float*)((char*)d_ws + (size_t)OUT_FEAT * KDIM * 2);

    kan_prep<<<OUT_FEAT, 256, 0, stream>>>(coeff, scale_base, scale_spline, base_bias, Wb, bias);
    kan_gemm11<<<(NTOK / 64) * (OUT_FEAT / 128), 256, 0, stream>>>(x, Wb, bias, out);
}

// Round 3
// 139.037 us; speedup vs baseline: 1.0296x; 1.0296x over previous
//
#include <hip/hip_runtime.h>
#include <hip/hip_bf16.h>

// KAN linear == GEMM M=8192, N=512, K=4096 (8 Chebyshev/silu feats per input,
// basis_0 folded into bias). Round 12: R11 showed occupancy is GRID-bound
// (512 blocks / 256 CU = 2 blk/CU) — LDS cuts alone bought nothing. R12:
// 64m x 64n blocks -> grid 1024 = exactly 4 blk/CU (16 waves/CU, 2x R9),
// while KEEPING 32 iters (K-step 128/iter, 64 per split-K half) so per-iter
// barrier count matches R9 not R11. Waves = 2wm x 2kk (tile 32m x 64n):
// in-block gen covers (token x input) exactly once. LDS 40960 B: Bs 32K
// (dbuf, XOR-8 swizzle as R9) + xsl 8K. Exact 4-block LDS fit (4x40960=160K).
#define IN_FEAT 512
#define OUT_FEAT 512
#define NTOK 8192
#define KDIM 4096

typedef short bf16x8 __attribute__((ext_vector_type(8)));
typedef float f32x16 __attribute__((ext_vector_type(16)));

static __device__ inline short f2bf(float f) {
    union { float f; unsigned u; } v; v.f = f;
    unsigned u = v.u;
    u += 0x7fffu + ((u >> 16) & 1u);   // RNE
    return (short)(u >> 16);
}

static __device__ inline unsigned pack2bf(float f0, float f1) {
    union { float f; unsigned u; } a, b; a.f = f0; b.f = f1;
    return __builtin_amdgcn_perm(b.u + 0x8000u, a.u + 0x8000u, 0x07060302u);
}

// 8 basis features of one (token,input): [silu(xc), xc, T2..T7]
static __device__ inline bf16x8 gen_chunk(float xv) {
    float xc = fminf(fmaxf(xv, -1.f), 1.f);
    float e  = __expf(-xc);
    float bse = xc * __builtin_amdgcn_rcpf(1.f + e);
    float b2 = 2.f * xc * xc - 1.f;
    float b3 = 2.f * xc * b2 - 1.f;
    float b4 = 2.f * xc * b3 - 1.f;
    float b5 = 2.f * xc * b4 - 1.f;
    float b6 = 2.f * xc * b5 - 1.f;
    float b7 = 2.f * xc * b6 - 1.f;
    union { uint4 u; bf16x8 v; } r;
    r.u.x = pack2bf(bse, xc);
    r.u.y = pack2bf(b2, b3);
    r.u.z = pack2bf(b4, b5);
    r.u.w = pack2bf(b6, b7);
    return r.v;
}

static __device__ inline void gload_lds16(const short* g, short* l) {
    __builtin_amdgcn_global_load_lds(
        (const __attribute__((address_space(1))) unsigned int*)g,
        (__attribute__((address_space(3))) unsigned int*)l,
        16, 0, 0);
}

// ---------------- prep: W bf16 [512 x 4096] + folded bias ----------------
__global__ __launch_bounds__(256) void kan_prep(
    const float* __restrict__ coeff, const float* __restrict__ scale_base,
    const float* __restrict__ scale_spline, const float* __restrict__ base_bias,
    short* __restrict__ Wb, float* __restrict__ bias)
{
    int o = blockIdx.x;
    int tid = threadIdx.x;
    float local = 0.f;
#pragma unroll
    for (int rep = 0; rep < 2; ++rep) {
        int i = tid + rep * 256;
        size_t oi = (size_t)o * IN_FEAT + i;
        const float4* c4 = (const float4*)(coeff + oi * 8);
        float4 ca = c4[0], cb = c4[1];
        float ss = scale_spline[oi];
        float sb = scale_base[oi];
        local += base_bias[oi] + ss * ca.x;
        bf16x8 w;
        w[0] = f2bf(sb);
        w[1] = f2bf(ss * ca.y); w[2] = f2bf(ss * ca.z); w[3] = f2bf(ss * ca.w);
        w[4] = f2bf(ss * cb.x); w[5] = f2bf(ss * cb.y); w[6] = f2bf(ss * cb.z);
        w[7] = f2bf(ss * cb.w);
        *(bf16x8*)(Wb + (size_t)o * KDIM + (size_t)i * 8) = w;
    }
    __shared__ float red[4];
    for (int off = 32; off > 0; off >>= 1) local += __shfl_down(local, off, 64);
    int lane = tid & 63, wv = tid >> 6;
    if (lane == 0) red[wv] = local;
    __syncthreads();
    if (tid == 0) bias[o] = red[0] + red[1] + red[2] + red[3];
}

// --- 32x32x16 fused GEMM, 64m x 64n blocks, split-K x2, 40 KB LDS, 4 blk/CU ---
#define RSTR 33   // epilogue reduce stride (floats): lane -> bank lane%32, 2-way

__global__ __launch_bounds__(256, 4) void kan_gemm12(
    const float* __restrict__ x, const short* __restrict__ Wb,
    const float* __restrict__ bias, float* __restrict__ out)
{
    // LDS pool, 40960 B:
    //   Bs: [2 buf][2 khalf][64 rows][8 slots][8 shorts]  32 KB (XOR-swizzled)
    //   xsl:[2 buf][16 inputs][64 tokens] f32               8 KB
    __shared__ __align__(16) short POOL[20480];
    short* Bs  = POOL;                    // [2][8192]
    float* xsl = (float*)(POOL + 16384);  // [2][1024]

    int tid = threadIdx.x;
    int nb = blockIdx.x & 7;         // XCD j sees nb=j -> 0.5 MB W slice per XCD L2
    int mb = blockIdx.x >> 3;        // 128 m-tiles
    int m0 = mb * 64, o0 = nb * 64;

    int lane = tid & 63, wv = tid >> 6;
    int wm = wv & 1, kk = wv >> 1;   // wave = 32m x 64n on K-half kk
    int l31 = lane & 31, half = lane >> 5;

    f32x16 acc[2];                   // [fn], 32x32 each
    acc[0] = (f32x16)0.f; acc[1] = (f32x16)0.f;

    // B DMA: wave wv stages khalf (wv>>1), rows [(wv&1)*32, +32), 4 calls.
    // phys slot s at row r holds logical chunk g = s ^ (r&7); source pre-swizzled.
    int rg = lane >> 3;              // row within 8-row group; row&7 == rg
    int g  = (lane & 7) ^ rg;        // logical input index 0..7 within the step
    int kh = wv >> 1, rb = (wv & 1) * 32;
    const short* Bg = Wb + (size_t)(o0 + rb + rg) * KDIM + kh * 2048 + g * 8;
    int bdst0 = kh * 4096 + rb * 64; // shorts within Bs[buf]

    // x staging: thread -> (row, 4 consecutive input-slots); float4 per iter.
    // slot s16 = p*4+j == kh*8+g with kh=p>>1, g=(p&1)*4+j.
    int xrow = tid >> 2, p = tid & 3;
    const float* xg = x + (size_t)(m0 + xrow) * IN_FEAT + (p >> 1) * 256 + (p & 1) * 4;
    int sb0 = (p * 4) * 64 + xrow;

#define STAGE(buf, it)                                                        \
    {                                                                         \
        short* bd_ = Bs + (buf) * 8192 + bdst0;                               \
        const short* bg_ = Bg + (size_t)(it) * 64;                            \
        _Pragma("unroll")                                                     \
        for (int j = 0; j < 4; ++j)                                           \
            gload_lds16(bg_ + (size_t)j * 8 * KDIM, bd_ + j * 512);           \
        float4 v_ = *(const float4*)(xg + (size_t)(it) * 8);                  \
        float* xd_ = xsl + (buf) * 1024 + sb0;                                \
        xd_[0]   = v_.x;                                                      \
        xd_[64]  = v_.y;                                                      \
        xd_[128] = v_.z;                                                      \
        xd_[192] = v_.w;                                                      \
    }

    STAGE(0, 0);
    int cur = 0;
    for (int it = 0; it < 32; ++it, cur ^= 1) {   // 32 x 128 k-elems = 4096
        __syncthreads();             // buf[cur] ready (DMA+writes drained); buf[nxt] free
        if (it < 31) { int nxt = cur ^ 1; STAGE(nxt, it + 1); }
        const short* Bsc = Bs + cur * 8192 + kk * 4096;
        const float* xc_ = xsl + cur * 1024;
#pragma unroll
        for (int istep = 0; istep < 4; ++istep) {   // 4 k-steps of 16 (2 inputs each)
            int clog = istep * 2 + half;            // this lane's logical chunk
            bf16x8 bfr[2], af;
#pragma unroll
            for (int fn = 0; fn < 2; ++fn) {
                int row = fn * 32 + l31;
                bfr[fn] = *(const bf16x8*)(Bsc + row * 64 + ((clog ^ (row & 7)) * 8));
            }
            af = gen_chunk(xc_[(kk * 8 + istep * 2 + half) * 64 + wm * 32 + l31]);
#pragma unroll
            for (int fn = 0; fn < 2; ++fn)
                acc[fn] = __builtin_amdgcn_mfma_f32_32x32x16_bf16(
                    af, bfr[fn], acc[fn], 0, 0, 0);
        }
    }
#undef STAGE

    // ---- epilogue: reduce the 2 K-halves through LDS (reuse pool), store ----
    float* rbuf = (float*)POOL;      // 10240 floats; max index 127*33+31 = 4222
    int base = (wm * 64 + lane) * RSTR;
    __syncthreads();                 // everyone done reading Bs/xsl
    if (kk == 1) {
#pragma unroll
        for (int fn = 0; fn < 2; ++fn)
#pragma unroll
            for (int r = 0; r < 16; ++r)
                rbuf[base + fn * 16 + r] = acc[fn][r];
    }
    __syncthreads();
    if (kk == 0) {
        // C/D layout (32x32): col = lane&31, row = (r&3) + 8*(r>>2) + 4*(lane>>5)
#pragma unroll
        for (int fn = 0; fn < 2; ++fn) {
            int o = o0 + fn * 32 + l31;
            float bv = bias[o];
#pragma unroll
            for (int r = 0; r < 16; ++r) {
                float v = acc[fn][r] + rbuf[base + fn * 16 + r] + bv;
                int token = m0 + wm * 32 + (r & 3) + 8 * (r >> 2) + 4 * half;
                out[(size_t)token * OUT_FEAT + o] = v;
            }
        }
    }
}

extern "C" void kernel_launch(void* const* d_in, const int* in_sizes, int n_in,
                              void* d_out, int out_size, void* d_ws, size_t ws_size,
                              hipStream_t stream) {
    const float* x            = (const float*)d_in[0];
    const float* coeff        = (const float*)d_in[1];
    const float* scale_base   = (const float*)d_in[2];
    const float* scale_spline = (const float*)d_in[3];
    const float* base_bias    = (const float*)d_in[4];
    float* out = (float*)d_out;

    short* Wb   = (short*)d_ws;                                  // 4 MB
    float* bias = (float*)((char*)d_ws + (size_t)OUT_FEAT * KDIM * 2);

    kan_prep<<<OUT_FEAT, 256, 0, stream>>>(coeff, scale_base, scale_spline, base_bias, Wb, bias);
    kan_gemm12<<<(NTOK / 64) * (OUT_FEAT / 64), 256, 0, stream>>>(x, Wb, bias, out);
}

// Round 4
// 137.656 us; speedup vs baseline: 1.0399x; 1.0100x over previous
//
#include <hip/hip_runtime.h>
#include <hip/hip_bf16.h>

// KAN linear == GEMM M=8192, N=512, K=4096 (8 Chebyshev/silu feats per input,
// basis_0 folded into bias). Round 13: R12 showed the limiter is the per-CU
// LDS pipe (structural ~35us + 12us bank conflicts of the 67us), not
// occupancy. Two LDS cuts, same verified math everywhere else:
//  1) waves = 4 K-quarters (wave tile 64m x 64n): every B element read by
//     exactly ONE wave (B-frag LDS reads halved vs R12's 2 wm-waves).
//  2) xsl token-XOR swizzle (addr = s*64 + (tok ^ ((s>>2)*8))): staging
//     writes and gen reads both 2-way (free) in the same 8 KB footprint.
// Bs: K-step 128 = [2][64 rows][16 slots][8 shorts], phys = clog ^ (row&15)
// (same involution as R9/R12, extended mod 16). LDS 40960 B = exact 4 blk/CU.
// Epilogue: 2-phase 4-way split-K reduce through stride-66 LDS slabs.
#define IN_FEAT 512
#define OUT_FEAT 512
#define NTOK 8192
#define KDIM 4096

typedef short bf16x8 __attribute__((ext_vector_type(8)));
typedef float f32x16 __attribute__((ext_vector_type(16)));

static __device__ inline short f2bf(float f) {
    union { float f; unsigned u; } v; v.f = f;
    unsigned u = v.u;
    u += 0x7fffu + ((u >> 16) & 1u);   // RNE
    return (short)(u >> 16);
}

static __device__ inline unsigned pack2bf(float f0, float f1) {
    union { float f; unsigned u; } a, b; a.f = f0; b.f = f1;
    return __builtin_amdgcn_perm(b.u + 0x8000u, a.u + 0x8000u, 0x07060302u);
}

// 8 basis features of one (token,input): [silu(xc), xc, T2..T7]
static __device__ inline bf16x8 gen_chunk(float xv) {
    float xc = fminf(fmaxf(xv, -1.f), 1.f);
    float e  = __expf(-xc);
    float bse = xc * __builtin_amdgcn_rcpf(1.f + e);
    float b2 = 2.f * xc * xc - 1.f;
    float b3 = 2.f * xc * b2 - 1.f;
    float b4 = 2.f * xc * b3 - 1.f;
    float b5 = 2.f * xc * b4 - 1.f;
    float b6 = 2.f * xc * b5 - 1.f;
    float b7 = 2.f * xc * b6 - 1.f;
    union { uint4 u; bf16x8 v; } r;
    r.u.x = pack2bf(bse, xc);
    r.u.y = pack2bf(b2, b3);
    r.u.z = pack2bf(b4, b5);
    r.u.w = pack2bf(b6, b7);
    return r.v;
}

static __device__ inline void gload_lds16(const short* g, short* l) {
    __builtin_amdgcn_global_load_lds(
        (const __attribute__((address_space(1))) unsigned int*)g,
        (__attribute__((address_space(3))) unsigned int*)l,
        16, 0, 0);
}

// ---------------- prep: W bf16 [512 x 4096] + folded bias ----------------
__global__ __launch_bounds__(256) void kan_prep(
    const float* __restrict__ coeff, const float* __restrict__ scale_base,
    const float* __restrict__ scale_spline, const float* __restrict__ base_bias,
    short* __restrict__ Wb, float* __restrict__ bias)
{
    int o = blockIdx.x;
    int tid = threadIdx.x;
    float local = 0.f;
#pragma unroll
    for (int rep = 0; rep < 2; ++rep) {
        int i = tid + rep * 256;
        size_t oi = (size_t)o * IN_FEAT + i;
        const float4* c4 = (const float4*)(coeff + oi * 8);
        float4 ca = c4[0], cb = c4[1];
        float ss = scale_spline[oi];
        float sb = scale_base[oi];
        local += base_bias[oi] + ss * ca.x;
        bf16x8 w;
        w[0] = f2bf(sb);
        w[1] = f2bf(ss * ca.y); w[2] = f2bf(ss * ca.z); w[3] = f2bf(ss * ca.w);
        w[4] = f2bf(ss * cb.x); w[5] = f2bf(ss * cb.y); w[6] = f2bf(ss * cb.z);
        w[7] = f2bf(ss * cb.w);
        *(bf16x8*)(Wb + (size_t)o * KDIM + (size_t)i * 8) = w;
    }
    __shared__ float red[4];
    for (int off = 32; off > 0; off >>= 1) local += __shfl_down(local, off, 64);
    int lane = tid & 63, wv = tid >> 6;
    if (lane == 0) red[wv] = local;
    __syncthreads();
    if (tid == 0) bias[o] = red[0] + red[1] + red[2] + red[3];
}

// --- 32x32x16 fused GEMM, 64m x 64n blocks, 4-way split-K waves, 40 KB LDS ---
__global__ __launch_bounds__(256, 4) void kan_gemm13(
    const float* __restrict__ x, const short* __restrict__ Wb,
    const float* __restrict__ bias, float* __restrict__ out)
{
    // LDS pool, 40960 B:
    //   Bs: [2 buf][64 rows][16 slots][8 shorts]  32 KB; phys = clog ^ (row&15)
    //   xsl:[2 buf][16 slots][64 tokens] f32       8 KB; tok-phys = tok^((s>>2)*8)
    __shared__ __align__(16) short POOL[20480];
    short* Bs  = POOL;                    // [2][8192]
    float* xsl = (float*)(POOL + 16384);  // [2][1024]

    int tid = threadIdx.x;
    int nb = blockIdx.x & 7;         // XCD j sees nb=j -> 0.5 MB W slice per XCD L2
    int mb = blockIdx.x >> 3;        // 128 m-tiles
    int m0 = mb * 64, o0 = nb * 64;

    int lane = tid & 63, wv = tid >> 6;
    int kk = wv;                     // wave = 64m x 64n on K-quarter kk
    int l31 = lane & 31, half = lane >> 5;
    int rm  = l31 & 15;              // Bs row & 15 for both fn rows (fn*32 ≡ 0)
    int xr0 = l31 ^ (kk * 8);        // xsl token-phys for fm=0 (fm*32 bit clear)

    f32x16 acc[2][2];                // [fm][fn], 32x32 each
#pragma unroll
    for (int a = 0; a < 2; ++a)
#pragma unroll
        for (int b = 0; b < 2; ++b) acc[a][b] = (f32x16)0.f;

    // B DMA: wave wv stages rows [wv*16,+16), 4 calls of 4 rows x 16 slots.
    // call c, lane i: row = wv*16 + c*4 + (i>>4), phys slot = i&15 holds
    // logical g = (i&15) ^ (c*4 + (i>>4))  (== phys ^ (row&15)).
    int rl = lane >> 4, q = lane & 15;
    const short* pB0 = Wb + (size_t)(o0 + wv * 16 +  0 + rl) * KDIM + (size_t)(q ^ ( 0 + rl)) * 8;
    const short* pB1 = Wb + (size_t)(o0 + wv * 16 +  4 + rl) * KDIM + (size_t)(q ^ ( 4 + rl)) * 8;
    const short* pB2 = Wb + (size_t)(o0 + wv * 16 +  8 + rl) * KDIM + (size_t)(q ^ ( 8 + rl)) * 8;
    const short* pB3 = Wb + (size_t)(o0 + wv * 16 + 12 + rl) * KDIM + (size_t)(q ^ (12 + rl)) * 8;

    // x staging: thread (xrow = tid>>2, p = tid&3) stages slots p*4..p*4+3 of
    // token xrow; float4 at xg + it*16 covers inputs it*16 + p*4 + j.
    int xrow = tid >> 2, p = tid & 3;
    const float* xg = x + (size_t)(m0 + xrow) * IN_FEAT + p * 4;
    int xb = p * 256 + (xrow ^ (p * 8));   // base: slot p*4 at swizzled token

#define STAGE(buf, it)                                                        \
    {                                                                         \
        short* bd_ = Bs + (buf) * 8192 + wv * 2048;                           \
        gload_lds16(pB0 + (size_t)(it) * 128, bd_);                           \
        gload_lds16(pB1 + (size_t)(it) * 128, bd_ + 512);                     \
        gload_lds16(pB2 + (size_t)(it) * 128, bd_ + 1024);                    \
        gload_lds16(pB3 + (size_t)(it) * 128, bd_ + 1536);                    \
        float4 v_ = *(const float4*)(xg + (size_t)(it) * 16);                 \
        float* xd_ = xsl + (buf) * 1024 + xb;                                 \
        xd_[0]   = v_.x;                                                      \
        xd_[64]  = v_.y;                                                      \
        xd_[128] = v_.z;                                                      \
        xd_[192] = v_.w;                                                      \
    }

    STAGE(0, 0);
    int cur = 0;
    for (int it = 0; it < 32; ++it, cur ^= 1) {   // 32 x 128 k-elems = 4096
        __syncthreads();             // buf[cur] ready (DMA+writes drained); buf[nxt] free
        if (it < 31) { int nxt = cur ^ 1; STAGE(nxt, it + 1); }
        const short* Bsc = Bs + cur * 8192;
        const float* xc_ = xsl + cur * 1024;
#pragma unroll
        for (int istep = 0; istep < 2; ++istep) {   // 2 k-steps of 16 (2 inputs each)
            int s = kk * 4 + istep * 2 + half;      // A slot == B logical chunk
            bf16x8 af0 = gen_chunk(xc_[s * 64 + xr0]);        // fm=0: tokens l31
            bf16x8 af1 = gen_chunk(xc_[s * 64 + 32 + xr0]);   // fm=1: tokens 32+l31
            int ph = (s ^ rm) * 8;
            bf16x8 b0 = *(const bf16x8*)(Bsc + l31 * 128 + ph);
            bf16x8 b1 = *(const bf16x8*)(Bsc + (32 + l31) * 128 + ph);
            acc[0][0] = __builtin_amdgcn_mfma_f32_32x32x16_bf16(af0, b0, acc[0][0], 0, 0, 0);
            acc[0][1] = __builtin_amdgcn_mfma_f32_32x32x16_bf16(af0, b1, acc[0][1], 0, 0, 0);
            acc[1][0] = __builtin_amdgcn_mfma_f32_32x32x16_bf16(af1, b0, acc[1][0], 0, 0, 0);
            acc[1][1] = __builtin_amdgcn_mfma_f32_32x32x16_bf16(af1, b1, acc[1][1], 0, 0, 0);
        }
    }
#undef STAGE

    // ---- epilogue: 4-way split-K reduce through LDS (reuse pool), store ----
    // slabs: lane L, value idx v (0..63) at slab + L*66 + v  (2-way banks).
    float* rbuf = (float*)POOL;      // 10240 floats; max used 4224+4221 = 8445
    __syncthreads();                 // everyone done reading Bs/xsl
    if (kk >= 2) {                   // kk=2 -> slab 0, kk=3 -> slab 1
        float* s_ = rbuf + (size_t)(kk - 2) * 4224 + lane * 66;
#pragma unroll
        for (int fm = 0; fm < 2; ++fm)
#pragma unroll
            for (int fn = 0; fn < 2; ++fn)
#pragma unroll
                for (int r = 0; r < 16; ++r)
                    s_[(fm * 2 + fn) * 16 + r] = acc[fm][fn][r];
    }
    __syncthreads();
    if (kk < 2) {                    // kk0 += kk2, kk1 += kk3
        const float* s_ = rbuf + (size_t)kk * 4224 + lane * 66;
#pragma unroll
        for (int fm = 0; fm < 2; ++fm)
#pragma unroll
            for (int fn = 0; fn < 2; ++fn)
#pragma unroll
                for (int r = 0; r < 16; ++r)
                    acc[fm][fn][r] += s_[(fm * 2 + fn) * 16 + r];
    }
    __syncthreads();
    if (kk == 1) {                   // kk1 partial -> slab 0
        float* s_ = rbuf + lane * 66;
#pragma unroll
        for (int fm = 0; fm < 2; ++fm)
#pragma unroll
            for (int fn = 0; fn < 2; ++fn)
#pragma unroll
                for (int r = 0; r < 16; ++r)
                    s_[(fm * 2 + fn) * 16 + r] = acc[fm][fn][r];
    }
    __syncthreads();
    if (kk == 0) {
        const float* s_ = rbuf + lane * 66;
        // C/D layout (32x32): col = lane&31, row = (r&3) + 8*(r>>2) + 4*(lane>>5)
#pragma unroll
        for (int fn = 0; fn < 2; ++fn) {
            int o = o0 + fn * 32 + l31;
            float bv = bias[o];
#pragma unroll
            for (int fm = 0; fm < 2; ++fm) {
#pragma unroll
                for (int r = 0; r < 16; ++r) {
                    float v = acc[fm][fn][r] + s_[(fm * 2 + fn) * 16 + r] + bv;
                    int token = m0 + fm * 32 + (r & 3) + 8 * (r >> 2) + 4 * half;
                    out[(size_t)token * OUT_FEAT + o] = v;
                }
            }
        }
    }
}

extern "C" void kernel_launch(void* const* d_in, const int* in_sizes, int n_in,
                              void* d_out, int out_size, void* d_ws, size_t ws_size,
                              hipStream_t stream) {
    const float* x            = (const float*)d_in[0];
    const float* coeff        = (const float*)d_in[1];
    const float* scale_base   = (const float*)d_in[2];
    const float* scale_spline = (const float*)d_in[3];
    const float* base_bias    = (const float*)d_in[4];
    float* out = (float*)d_out;

    short* Wb   = (short*)d_ws;                                  // 4 MB
    float* bias = (float*)((char*)d_ws + (size_t)OUT_FEAT * KDIM * 2);

    kan_prep<<<OUT_FEAT, 256, 0, stream>>>(coeff, scale_base, scale_spline, base_bias, Wb, bias);
    kan_gemm13<<<(NTOK / 64) * (OUT_FEAT / 64), 256, 0, stream>>>(x, Wb, bias, out);
}